// Round 11
// baseline (83.053 us; speedup 1.0000x reference)
//
#include <hip/hip_runtime.h>
#include <math.h>

#define NJ 7
#define DTF 0.01f
#define GRAVF 9.81f
#define MIX(i,j) ((i)*((i)+1)/2 + (j))
#define MPAD 29   // s_M stride (gcd(29,32)=1 -> free 2-way)
#define FSTR 43   // per-lane F stride (gcd(43,32)=1)
#define SNC  15   // sn/cs stride
#define QST  9    // qd/rhs stride

__device__ __forceinline__ void cross3(const float* a, const float* b, float* o){
    o[0] = a[1]*b[2] - a[2]*b[1];
    o[1] = a[2]*b[0] - a[0]*b[2];
    o[2] = a[0]*b[1] - a[1]*b[0];
}
__device__ __forceinline__ void mv3(const float* E, const float* x, float* y){
    y[0] = E[0]*x[0] + E[1]*x[1] + E[2]*x[2];
    y[1] = E[3]*x[0] + E[4]*x[1] + E[5]*x[2];
    y[2] = E[6]*x[0] + E[7]*x[1] + E[8]*x[2];
}
__device__ __forceinline__ void mtv3(const float* E, const float* x, float* y){
    y[0] = E[0]*x[0] + E[3]*x[1] + E[6]*x[2];
    y[1] = E[1]*x[0] + E[4]*x[1] + E[7]*x[2];
    y[2] = E[2]*x[0] + E[5]*x[1] + E[8]*x[2];
}
__device__ __forceinline__ void symv(const float* S, const float* x, float* y){
    y[0] = S[0]*x[0] + S[1]*x[1] + S[2]*x[2];
    y[1] = S[1]*x[0] + S[3]*x[1] + S[4]*x[2];
    y[2] = S[2]*x[0] + S[4]*x[1] + S[5]*x[2];
}
__device__ __forceinline__ void mm3(const float* A, const float* B, float* o){
#pragma unroll
    for (int r = 0; r < 3; r++)
#pragma unroll
        for (int c = 0; c < 3; c++)
            o[r*3+c] = A[r*3]*B[c] + A[r*3+1]*B[3+c] + A[r*3+2]*B[6+c];
}
// o = E^T X E
__device__ __forceinline__ void congr(const float* E, const float* X, float* o){
    float t[9];
#pragma unroll
    for (int r = 0; r < 3; r++)
#pragma unroll
        for (int c = 0; c < 3; c++)
            t[r*3+c] = E[r]*X[c] + E[3+r]*X[3+c] + E[6+r]*X[6+c];
    mm3(t, E, o);
}
// E_i = R(q_i)^T @ R_tree[i]
__device__ __forceinline__ void makeE(const float* a, const float* __restrict__ Rt,
                                      float s, float c, float* E){
    float omc = 1.0f - c;
    float RT[9];
    RT[0] = c + omc*a[0]*a[0];       RT[1] =  s*a[2] + omc*a[0]*a[1]; RT[2] = -s*a[1] + omc*a[0]*a[2];
    RT[3] = -s*a[2] + omc*a[1]*a[0]; RT[4] = c + omc*a[1]*a[1];       RT[5] =  s*a[0] + omc*a[1]*a[2];
    RT[6] =  s*a[1] + omc*a[2]*a[0]; RT[7] = -s*a[0] + omc*a[2]*a[1]; RT[8] = c + omc*a[2]*a[2];
    float Rl[9];
#pragma unroll
    for (int k = 0; k < 9; k++) Rl[k] = Rt[k];
    mm3(RT, Rl, E);
}
// body spatial-inertia params (wave-uniform scalar loads)
__device__ __forceinline__ void bodyI(const float* __restrict__ g_I, int i,
                                      float* SA, float* h, float& m){
    const float* I6 = g_I + i*36;
    SA[0]=I6[0]; SA[1]=I6[1]; SA[2]=I6[2];
    SA[3]=I6[7]; SA[4]=I6[8]; SA[5]=I6[14];
    h[0]=I6[16]; h[1]=I6[5]; h[2]=I6[9];
    m = I6[21];
}

__constant__ float QL_c[NJ] = {-2.9671f,-1.8326f,-2.9671f,-3.1416f,-2.9671f,-0.0873f,-2.9671f};
__constant__ float QU_c[NJ] = { 2.9671f, 1.8326f, 2.9671f, 0.0f,    2.9671f, 3.8223f, 2.9671f};

// Block = 192 = 3 waves on the SAME 64 elements.
// Wave 0: link-frame RNEA -> rhs; after barrier: Cholesky + solves + store.
// Waves 1,2: link-frame CRBA; F columns split by wave-uniform ownership:
//   wave1 owns k in {0,5,6}, wave2 owns k in {1,2,3,4} (14/14 transform pairs).
// Both CRBA waves duplicate the serial composite-inertia chain (registers);
// F slots and M entries are owner-disjoint -> no races, no extra syncs.
__global__ __launch_bounds__(192)
void panda_step(const float* __restrict__ x, const float* __restrict__ u,
                const float* __restrict__ g_ax, const float* __restrict__ g_Rt,
                const float* __restrict__ g_pt, const float* __restrict__ g_I,
                float* __restrict__ out, int B)
{
    __shared__ float s_M[64*MPAD];     // 7424 B
    __shared__ float s_F[2*64*FSTR];   // 22016 B (role0: FF, roles1/2: Fk shared, disjoint slots)
    __shared__ float s_snc[64*SNC];    // 3840 B (sn[0:7), cs[7:14))
    __shared__ float s_qd[64*QST];     // 2304 B
    __shared__ float s_rhs[64*QST];    // 2304 B

    const int role = threadIdx.x >> 6;      // 0,1,2 wave-uniform
    const int lane = threadIdx.x & 63;
    const int e    = blockIdx.x*64 + lane;
    const bool act = (e < B);

    float q[NJ], qd[NJ];
    if (act && role == 0){
        float xl[14];
        const float2* x2 = (const float2*)(x + e*14);
#pragma unroll
        for (int i = 0; i < 7; i++){ float2 v = x2[i]; xl[2*i] = v.x; xl[2*i+1] = v.y; }
#pragma unroll
        for (int i = 0; i < NJ; i++){
            q[i]  = fminf(fmaxf(xl[i], QL_c[i]), QU_c[i]);
            qd[i] = xl[NJ + i];
            float s, c; __sincosf(q[i], &s, &c);
            s_snc[lane*SNC + i]     = s;
            s_snc[lane*SNC + 7 + i] = c;
            s_qd[lane*QST + i]      = qd[i];
            s_rhs[lane*QST + i]     = u[e*NJ + i];
        }
    }
    __syncthreads();   // publish sn/cs/qd/rhs

    if (act && role >= 1){
        // =================== CRBA (rolled, k-ownership split) ===================
        float* Fb = &s_F[64*FSTR + lane*FSTR];
        const bool isW1 = (role == 1);
        float SA[6], hc[3], mc;
        bodyI(g_I, 6, SA, hc, mc);
#pragma unroll 1
        for (int i = NJ-1; i >= 0; --i){
            float a[3] = { g_ax[3*i], g_ax[3*i+1], g_ax[3*i+2] };
            float p[3] = { g_pt[3*i], g_pt[3*i+1], g_pt[3*i+2] };
            // F_i = [SA a ; a x hc] — created by owner(i)
            bool ownI = isW1 ? (i==0 || i>=5) : (i>=1 && i<=4);
            if (ownI){
                float Ft[3]; symv(SA, a, Ft);
                Fb[i*6+0]=Ft[0]; Fb[i*6+1]=Ft[1]; Fb[i*6+2]=Ft[2];
                Fb[i*6+3] = a[1]*hc[2] - a[2]*hc[1];
                Fb[i*6+4] = a[2]*hc[0] - a[0]*hc[2];
                Fb[i*6+5] = a[0]*hc[1] - a[1]*hc[0];
            }
            // M column i, owned k's only
#pragma unroll 1
            for (int k = i; k < NJ; ++k){
                bool own = isW1 ? (k==0 || k>=5) : (k>=1 && k<=4);
                if (own){
                    float f0=Fb[k*6], f1=Fb[k*6+1], f2=Fb[k*6+2];
                    s_M[lane*MPAD + k*(k+1)/2 + i] = a[0]*f0 + a[1]*f1 + a[2]*f2;
                }
            }
            if (i > 0){
                float snv = s_snc[lane*SNC+i], csv = s_snc[lane*SNC+7+i];
                float E[9]; makeE(a, g_Rt + 9*i, snv, csv, E);
                float SAm[6], hm[3], mm_;
                bodyI(g_I, i-1, SAm, hm, mm_);
                float Af[9] = {SA[0],SA[1],SA[2], SA[1],SA[3],SA[4], SA[2],SA[4],SA[5]};
                float Ap[9]; congr(E, Af, Ap);
                float hr[3]; mtv3(E, hc, hr);
                float hpd = hr[0]*p[0]+hr[1]*p[1]+hr[2]*p[2];
                float ppd = p[0]*p[0]+p[1]*p[1]+p[2]*p[2];
                float dga = 2.0f*hpd + mc*ppd;
                SA[0] = Ap[0] - 2.0f*p[0]*hr[0] - mc*p[0]*p[0] + dga + SAm[0];
                SA[1] = Ap[1] - p[0]*hr[1] - hr[0]*p[1] - mc*p[0]*p[1] + SAm[1];
                SA[2] = Ap[2] - p[0]*hr[2] - hr[0]*p[2] - mc*p[0]*p[2] + SAm[2];
                SA[3] = Ap[4] - 2.0f*p[1]*hr[1] - mc*p[1]*p[1] + dga + SAm[3];
                SA[4] = Ap[5] - p[1]*hr[2] - hr[1]*p[2] - mc*p[1]*p[2] + SAm[4];
                SA[5] = Ap[8] - 2.0f*p[2]*hr[2] - mc*p[2]*p[2] + dga + SAm[5];
                hc[0] = hr[0] + mc*p[0] + hm[0];
                hc[1] = hr[1] + mc*p[1] + hm[1];
                hc[2] = hr[2] + mc*p[2] + hm[2];
                mc += mm_;
                // transform owned active F_k into frame i-1
#pragma unroll 1
                for (int k = i; k < NJ; ++k){
                    bool own = isW1 ? (k==0 || k>=5) : (k>=1 && k<=4);
                    if (own){
                        float ft[3] = {Fb[k*6+0], Fb[k*6+1], Fb[k*6+2]};
                        float fb[3] = {Fb[k*6+3], Fb[k*6+4], Fb[k*6+5]};
                        float tm[3], tf[3], cp[3];
                        mtv3(E, ft, tm); mtv3(E, fb, tf);
                        cross3(p, tf, cp);
                        Fb[k*6+0]=tm[0]+cp[0]; Fb[k*6+1]=tm[1]+cp[1]; Fb[k*6+2]=tm[2]+cp[2];
                        Fb[k*6+3]=tf[0];       Fb[k*6+4]=tf[1];       Fb[k*6+5]=tf[2];
                    }
                }
            }
        }
    }
    else if (act){
        // =================== RNEA (rolled) ===================
        float* Fb = &s_F[lane*FSTR];
        float w[3]  = {0.f,0.f,0.f}, vl[3] = {0.f,0.f,0.f};
        float aw[3] = {0.f,0.f,0.f}, av[3] = {0.f,0.f,GRAVF};
#pragma unroll 1
        for (int i = 0; i < NJ; ++i){
            float a[3] = { g_ax[3*i], g_ax[3*i+1], g_ax[3*i+2] };
            float p[3] = { g_pt[3*i], g_pt[3*i+1], g_pt[3*i+2] };
            float snv = s_snc[lane*SNC+i], csv = s_snc[lane*SNC+7+i];
            float qdi = s_qd[lane*QST+i];
            float E[9]; makeE(a, g_Rt + 9*i, snv, csv, E);
            float tw[3]; mv3(E, w, tw);
            float nw[3] = { tw[0]+a[0]*qdi, tw[1]+a[1]*qdi, tw[2]+a[2]*qdi };
            float cwp[3]; cross3(w, p, cwp);
            float t1[3] = { vl[0]+cwp[0], vl[1]+cwp[1], vl[2]+cwp[2] };
            float nvl[3]; mv3(E, t1, nvl);
            float taw[3]; mv3(E, aw, taw);
            float cna[3]; cross3(nw, a, cna);
            float naw[3] = { taw[0]+qdi*cna[0], taw[1]+qdi*cna[1], taw[2]+qdi*cna[2] };
            float cap[3]; cross3(aw, p, cap);
            float t2[3] = { av[0]+cap[0], av[1]+cap[1], av[2]+cap[2] };
            float tav[3]; mv3(E, t2, tav);
            float cva[3]; cross3(nvl, a, cva);
            float nav[3] = { tav[0]+qdi*cva[0], tav[1]+qdi*cva[1], tav[2]+qdi*cva[2] };
            float SAi[6], hi[3], mi; bodyI(g_I, i, SAi, hi, mi);
            float Ivt[3], Iat[3], hxv[3], hxa[3];
            symv(SAi, nw, Ivt);  cross3(hi, nvl, hxv);
            symv(SAi, naw, Iat); cross3(hi, nav, hxa);
#pragma unroll
            for (int k = 0; k < 3; k++){ Ivt[k] += hxv[k]; Iat[k] += hxa[k]; }
            float hxw[3], hxaw[3];
            cross3(hi, nw, hxw); cross3(hi, naw, hxaw);
            float Ivb[3] = { mi*nvl[0]-hxw[0], mi*nvl[1]-hxw[1], mi*nvl[2]-hxw[2] };
            float Iab[3] = { mi*nav[0]-hxaw[0], mi*nav[1]-hxaw[1], mi*nav[2]-hxaw[2] };
            float c1[3], c2[3], c3[3];
            cross3(nw, Ivt, c1); cross3(nvl, Ivb, c2); cross3(nw, Ivb, c3);
            Fb[i*6+0] = Iat[0]+c1[0]+c2[0];
            Fb[i*6+1] = Iat[1]+c1[1]+c2[1];
            Fb[i*6+2] = Iat[2]+c1[2]+c2[2];
            Fb[i*6+3] = Iab[0]+c3[0];
            Fb[i*6+4] = Iab[1]+c3[1];
            Fb[i*6+5] = Iab[2]+c3[2];
#pragma unroll
            for (int k = 0; k < 3; k++){ w[k]=nw[k]; vl[k]=nvl[k]; aw[k]=naw[k]; av[k]=nav[k]; }
        }
        // backward fold (rolled; E recomputed)
#pragma unroll 1
        for (int i = NJ-1; i >= 0; --i){
            float a[3] = { g_ax[3*i], g_ax[3*i+1], g_ax[3*i+2] };
            float f0=Fb[i*6+0], f1=Fb[i*6+1], f2=Fb[i*6+2];
            s_rhs[lane*QST+i] -= a[0]*f0 + a[1]*f1 + a[2]*f2;
            if (i > 0){
                float p[3] = { g_pt[3*i], g_pt[3*i+1], g_pt[3*i+2] };
                float snv = s_snc[lane*SNC+i], csv = s_snc[lane*SNC+7+i];
                float E[9]; makeE(a, g_Rt + 9*i, snv, csv, E);
                float ftop[3] = {f0, f1, f2};
                float fbot[3] = {Fb[i*6+3], Fb[i*6+4], Fb[i*6+5]};
                float tm[3], tf[3], cp[3];
                mtv3(E, ftop, tm); mtv3(E, fbot, tf);
                cross3(p, tf, cp);
                Fb[(i-1)*6+0] += tm[0]+cp[0];
                Fb[(i-1)*6+1] += tm[1]+cp[1];
                Fb[(i-1)*6+2] += tm[2]+cp[2];
                Fb[(i-1)*6+3] += tf[0];
                Fb[(i-1)*6+4] += tf[1];
                Fb[(i-1)*6+5] += tf[2];
            }
        }
    }

    __syncthreads();

    if (act && role == 0){
        // ======== ridge + Cholesky + triangular solves + integrate + store ========
        float Mx[28];
#pragma unroll
        for (int j = 0; j < 28; j++) Mx[j] = s_M[lane*MPAD + j];
#pragma unroll
        for (int i = 0; i < NJ; i++) Mx[MIX(i,i)] += 1e-8f;
#pragma unroll
        for (int k = 0; k < NJ; k++){
            float d = Mx[MIX(k,k)];
#pragma unroll
            for (int j = 0; j < NJ; j++) if (j < k) d -= Mx[MIX(k,j)]*Mx[MIX(k,j)];
            float linv = __builtin_amdgcn_rsqf(d);
            Mx[MIX(k,k)] = linv;
#pragma unroll
            for (int i2 = k+1; i2 < NJ; i2++){
                float s2 = Mx[MIX(i2,k)];
#pragma unroll
                for (int j = 0; j < NJ; j++) if (j < k) s2 -= Mx[MIX(i2,j)]*Mx[MIX(k,j)];
                Mx[MIX(i2,k)] = s2 * linv;
            }
        }
        float rhs[NJ];
#pragma unroll
        for (int i = 0; i < NJ; i++) rhs[i] = s_rhs[lane*QST + i];
        float y[NJ];
#pragma unroll
        for (int i = 0; i < NJ; i++){
            float s2 = rhs[i];
#pragma unroll
            for (int j = 0; j < NJ; j++) if (j < i) s2 -= Mx[MIX(i,j)]*y[j];
            y[i] = s2 * Mx[MIX(i,i)];
        }
        float z[NJ];
#pragma unroll
        for (int i = NJ-1; i >= 0; i--){
            float s2 = y[i];
#pragma unroll
            for (int j = NJ-1; j >= 0; j--) if (j > i) s2 -= Mx[MIX(j,i)]*z[j];
            z[i] = s2 * Mx[MIX(i,i)];
        }
        float o14[14];
#pragma unroll
        for (int i = 0; i < NJ; i++){
            float qdn = qd[i] + DTF*z[i];
            o14[i]      = q[i] + DTF*qdn;
            o14[NJ + i] = qdn;
        }
        float2* o2 = (float2*)(out + e*14);
#pragma unroll
        for (int i = 0; i < 7; i++){ float2 v; v.x = o14[2*i]; v.y = o14[2*i+1]; o2[i] = v; }
    }
}

extern "C" void kernel_launch(void* const* d_in, const int* in_sizes, int n_in,
                              void* d_out, int out_size, void* d_ws, size_t ws_size,
                              hipStream_t stream) {
    const float* x   = (const float*)d_in[0];
    const float* u   = (const float*)d_in[1];
    const float* ax  = (const float*)d_in[2];
    const float* Rt  = (const float*)d_in[3];
    const float* pt  = (const float*)d_in[4];
    const float* Isp = (const float*)d_in[5];
    float* out = (float*)d_out;
    int B = in_sizes[0] / 14;
    int grid = (B + 63) / 64;
    hipLaunchKernelGGL(panda_step, dim3(grid), dim3(192), 0, stream,
                       x, u, ax, Rt, pt, Isp, out, B);
}

// Round 12
// 77.618 us; speedup vs baseline: 1.0700x; 1.0700x over previous
//
#include <hip/hip_runtime.h>
#include <math.h>

#define NJ 7
#define DTF 0.01f
#define GRAVF 9.81f
#define MIX(i,j) ((i)*((i)+1)/2 + (j))
#define MPAD 29   // s_M stride (gcd(29,32)=1 -> free 2-way)
#define FSTR 43   // per-lane F stride (gcd(43,32)=1)
#define P0S  29   // role0 private stride: sn[0:7) cs[7:14) qd[14:21) rhs[21:28)
#define P1S  15   // role1 private stride: sn[0:7) cs[7:14)

__device__ __forceinline__ void cross3(const float* a, const float* b, float* o){
    o[0] = a[1]*b[2] - a[2]*b[1];
    o[1] = a[2]*b[0] - a[0]*b[2];
    o[2] = a[0]*b[1] - a[1]*b[0];
}
__device__ __forceinline__ void mv3(const float* E, const float* x, float* y){
    y[0] = E[0]*x[0] + E[1]*x[1] + E[2]*x[2];
    y[1] = E[3]*x[0] + E[4]*x[1] + E[5]*x[2];
    y[2] = E[6]*x[0] + E[7]*x[1] + E[8]*x[2];
}
__device__ __forceinline__ void mtv3(const float* E, const float* x, float* y){
    y[0] = E[0]*x[0] + E[3]*x[1] + E[6]*x[2];
    y[1] = E[1]*x[0] + E[4]*x[1] + E[7]*x[2];
    y[2] = E[2]*x[0] + E[5]*x[1] + E[8]*x[2];
}
__device__ __forceinline__ void symv(const float* S, const float* x, float* y){
    y[0] = S[0]*x[0] + S[1]*x[1] + S[2]*x[2];
    y[1] = S[1]*x[0] + S[3]*x[1] + S[4]*x[2];
    y[2] = S[2]*x[0] + S[4]*x[1] + S[5]*x[2];
}
__device__ __forceinline__ void mm3(const float* A, const float* B, float* o){
#pragma unroll
    for (int r = 0; r < 3; r++)
#pragma unroll
        for (int c = 0; c < 3; c++)
            o[r*3+c] = A[r*3]*B[c] + A[r*3+1]*B[3+c] + A[r*3+2]*B[6+c];
}
// o = E^T X E
__device__ __forceinline__ void congr(const float* E, const float* X, float* o){
    float t[9];
#pragma unroll
    for (int r = 0; r < 3; r++)
#pragma unroll
        for (int c = 0; c < 3; c++)
            t[r*3+c] = E[r]*X[c] + E[3+r]*X[3+c] + E[6+r]*X[6+c];
    mm3(t, E, o);
}
// E_i = R(q_i)^T @ R_tree[i]
__device__ __forceinline__ void makeE(const float* a, const float* __restrict__ Rt,
                                      float s, float c, float* E){
    float omc = 1.0f - c;
    float RT[9];
    RT[0] = c + omc*a[0]*a[0];       RT[1] =  s*a[2] + omc*a[0]*a[1]; RT[2] = -s*a[1] + omc*a[0]*a[2];
    RT[3] = -s*a[2] + omc*a[1]*a[0]; RT[4] = c + omc*a[1]*a[1];       RT[5] =  s*a[0] + omc*a[1]*a[2];
    RT[6] =  s*a[1] + omc*a[2]*a[0]; RT[7] = -s*a[0] + omc*a[2]*a[1]; RT[8] = c + omc*a[2]*a[2];
    float Rl[9];
#pragma unroll
    for (int k = 0; k < 9; k++) Rl[k] = Rt[k];
    mm3(RT, Rl, E);
}
// body spatial-inertia params (wave-uniform scalar loads)
__device__ __forceinline__ void bodyI(const float* __restrict__ g_I, int i,
                                      float* SA, float* h, float& m){
    const float* I6 = g_I + i*36;
    SA[0]=I6[0]; SA[1]=I6[1]; SA[2]=I6[2];
    SA[3]=I6[7]; SA[4]=I6[8]; SA[5]=I6[14];
    h[0]=I6[16]; h[1]=I6[5]; h[2]=I6[9];
    m = I6[21];
}

__constant__ float QL_c[NJ] = {-2.9671f,-1.8326f,-2.9671f,-3.1416f,-2.9671f,-0.0873f,-2.9671f};
__constant__ float QU_c[NJ] = { 2.9671f, 1.8326f, 2.9671f, 0.0f,    2.9671f, 3.8223f, 2.9671f};

// Block = 128 = 2 waves on the SAME 64 elements, fully decoupled until ONE
// barrier (only cross-wave data is s_M). Each wave computes its own sincos
// into a role-PRIVATE LDS region, so there is no produce-consume barrier.
// Wave 0: link-frame RNEA -> rhs; after barrier: Cholesky + solves + store.
// Wave 1: link-frame CRBA -> M (s_M) -> done.
__global__ __launch_bounds__(128)
void panda_step(const float* __restrict__ x, const float* __restrict__ u,
                const float* __restrict__ g_ax, const float* __restrict__ g_Rt,
                const float* __restrict__ g_pt, const float* __restrict__ g_I,
                float* __restrict__ out, int B)
{
    __shared__ float s_M[64*MPAD];     // 7424 B  (CRBA -> solve)
    __shared__ float s_F[2*64*FSTR];   // 22016 B (role0 lower, role1 upper)
    __shared__ float s_p0[64*P0S];     // 7424 B  role0 private: sn,cs,qd,rhs
    __shared__ float s_p1[64*P1S];     // 3840 B  role1 private: sn,cs
    // total 40704 B -> 4 blocks/CU (160 KiB exactly)

    const int role = threadIdx.x >> 6;      // wave-uniform
    const int lane = threadIdx.x & 63;
    const int e    = blockIdx.x*64 + lane;
    const bool act = (e < B);

    float q[NJ], qd[NJ];

    if (act && role == 1){
        // ---- own state: load q-half of x, sincos into private LDS ----
        {
            const float2* x2 = (const float2*)(x + e*14);
            float q8[8];
#pragma unroll
            for (int i = 0; i < 4; i++){ float2 v = x2[i]; q8[2*i] = v.x; q8[2*i+1] = v.y; }
#pragma unroll
            for (int i = 0; i < NJ; i++){
                float qi = fminf(fmaxf(q8[i], QL_c[i]), QU_c[i]);
                float s, c; __sincosf(qi, &s, &c);
                s_p1[lane*P1S + i]     = s;
                s_p1[lane*P1S + 7 + i] = c;
            }
        }
        // =================== CRBA (rolled) ===================
        float* Fb = &s_F[64*FSTR + lane*FSTR];
        float SA[6], hc[3], mc;
        bodyI(g_I, 6, SA, hc, mc);
#pragma unroll 1
        for (int i = NJ-1; i >= 0; --i){
            float a[3] = { g_ax[3*i], g_ax[3*i+1], g_ax[3*i+2] };
            float p[3] = { g_pt[3*i], g_pt[3*i+1], g_pt[3*i+2] };
            // F_i = [SA a ; a x hc]
            float Ft[3]; symv(SA, a, Ft);
            Fb[i*6+0]=Ft[0]; Fb[i*6+1]=Ft[1]; Fb[i*6+2]=Ft[2];
            Fb[i*6+3] = a[1]*hc[2] - a[2]*hc[1];
            Fb[i*6+4] = a[2]*hc[0] - a[0]*hc[2];
            Fb[i*6+5] = a[0]*hc[1] - a[1]*hc[0];
            // M column i
#pragma unroll 1
            for (int k = i; k < NJ; ++k){
                float f0=Fb[k*6], f1=Fb[k*6+1], f2=Fb[k*6+2];
                s_M[lane*MPAD + k*(k+1)/2 + i] = a[0]*f0 + a[1]*f1 + a[2]*f2;
            }
            if (i > 0){
                float snv = s_p1[lane*P1S+i], csv = s_p1[lane*P1S+7+i];
                float E[9]; makeE(a, g_Rt + 9*i, snv, csv, E);
                float SAm[6], hm[3], mm_;
                bodyI(g_I, i-1, SAm, hm, mm_);
                float Af[9] = {SA[0],SA[1],SA[2], SA[1],SA[3],SA[4], SA[2],SA[4],SA[5]};
                float Ap[9]; congr(E, Af, Ap);
                float hr[3]; mtv3(E, hc, hr);
                float hpd = hr[0]*p[0]+hr[1]*p[1]+hr[2]*p[2];
                float ppd = p[0]*p[0]+p[1]*p[1]+p[2]*p[2];
                float dga = 2.0f*hpd + mc*ppd;
                SA[0] = Ap[0] - 2.0f*p[0]*hr[0] - mc*p[0]*p[0] + dga + SAm[0];
                SA[1] = Ap[1] - p[0]*hr[1] - hr[0]*p[1] - mc*p[0]*p[1] + SAm[1];
                SA[2] = Ap[2] - p[0]*hr[2] - hr[0]*p[2] - mc*p[0]*p[2] + SAm[2];
                SA[3] = Ap[4] - 2.0f*p[1]*hr[1] - mc*p[1]*p[1] + dga + SAm[3];
                SA[4] = Ap[5] - p[1]*hr[2] - hr[1]*p[2] - mc*p[1]*p[2] + SAm[4];
                SA[5] = Ap[8] - 2.0f*p[2]*hr[2] - mc*p[2]*p[2] + dga + SAm[5];
                hc[0] = hr[0] + mc*p[0] + hm[0];
                hc[1] = hr[1] + mc*p[1] + hm[1];
                hc[2] = hr[2] + mc*p[2] + hm[2];
                mc += mm_;
                // transform active F_k into frame i-1
#pragma unroll 1
                for (int k = i; k < NJ; ++k){
                    float ft[3] = {Fb[k*6+0], Fb[k*6+1], Fb[k*6+2]};
                    float fb[3] = {Fb[k*6+3], Fb[k*6+4], Fb[k*6+5]};
                    float tm[3], tf[3], cp[3];
                    mtv3(E, ft, tm); mtv3(E, fb, tf);
                    cross3(p, tf, cp);
                    Fb[k*6+0]=tm[0]+cp[0]; Fb[k*6+1]=tm[1]+cp[1]; Fb[k*6+2]=tm[2]+cp[2];
                    Fb[k*6+3]=tf[0];       Fb[k*6+4]=tf[1];       Fb[k*6+5]=tf[2];
                }
            }
        }
    }
    else if (act){
        // ---- own state: full x row, sincos/qd/rhs into private LDS ----
        {
            float xl[14];
            const float2* x2 = (const float2*)(x + e*14);
#pragma unroll
            for (int i = 0; i < 7; i++){ float2 v = x2[i]; xl[2*i] = v.x; xl[2*i+1] = v.y; }
#pragma unroll
            for (int i = 0; i < NJ; i++){
                q[i]  = fminf(fmaxf(xl[i], QL_c[i]), QU_c[i]);
                qd[i] = xl[NJ + i];
                float s, c; __sincosf(q[i], &s, &c);
                s_p0[lane*P0S + i]      = s;
                s_p0[lane*P0S + 7 + i]  = c;
                s_p0[lane*P0S + 14 + i] = qd[i];
                s_p0[lane*P0S + 21 + i] = u[e*NJ + i];
            }
        }
        // =================== RNEA (rolled) ===================
        float* Fb = &s_F[lane*FSTR];
        float w[3]  = {0.f,0.f,0.f}, vl[3] = {0.f,0.f,0.f};
        float aw[3] = {0.f,0.f,0.f}, av[3] = {0.f,0.f,GRAVF};
#pragma unroll 1
        for (int i = 0; i < NJ; ++i){
            float a[3] = { g_ax[3*i], g_ax[3*i+1], g_ax[3*i+2] };
            float p[3] = { g_pt[3*i], g_pt[3*i+1], g_pt[3*i+2] };
            float snv = s_p0[lane*P0S+i], csv = s_p0[lane*P0S+7+i];
            float qdi = s_p0[lane*P0S+14+i];
            float E[9]; makeE(a, g_Rt + 9*i, snv, csv, E);
            float tw[3]; mv3(E, w, tw);
            float nw[3] = { tw[0]+a[0]*qdi, tw[1]+a[1]*qdi, tw[2]+a[2]*qdi };
            float cwp[3]; cross3(w, p, cwp);
            float t1[3] = { vl[0]+cwp[0], vl[1]+cwp[1], vl[2]+cwp[2] };
            float nvl[3]; mv3(E, t1, nvl);
            float taw[3]; mv3(E, aw, taw);
            float cna[3]; cross3(nw, a, cna);
            float naw[3] = { taw[0]+qdi*cna[0], taw[1]+qdi*cna[1], taw[2]+qdi*cna[2] };
            float cap[3]; cross3(aw, p, cap);
            float t2[3] = { av[0]+cap[0], av[1]+cap[1], av[2]+cap[2] };
            float tav[3]; mv3(E, t2, tav);
            float cva[3]; cross3(nvl, a, cva);
            float nav[3] = { tav[0]+qdi*cva[0], tav[1]+qdi*cva[1], tav[2]+qdi*cva[2] };
            float SAi[6], hi[3], mi; bodyI(g_I, i, SAi, hi, mi);
            float Ivt[3], Iat[3], hxv[3], hxa[3];
            symv(SAi, nw, Ivt);  cross3(hi, nvl, hxv);
            symv(SAi, naw, Iat); cross3(hi, nav, hxa);
#pragma unroll
            for (int k = 0; k < 3; k++){ Ivt[k] += hxv[k]; Iat[k] += hxa[k]; }
            float hxw[3], hxaw[3];
            cross3(hi, nw, hxw); cross3(hi, naw, hxaw);
            float Ivb[3] = { mi*nvl[0]-hxw[0], mi*nvl[1]-hxw[1], mi*nvl[2]-hxw[2] };
            float Iab[3] = { mi*nav[0]-hxaw[0], mi*nav[1]-hxaw[1], mi*nav[2]-hxaw[2] };
            float c1[3], c2[3], c3[3];
            cross3(nw, Ivt, c1); cross3(nvl, Ivb, c2); cross3(nw, Ivb, c3);
            Fb[i*6+0] = Iat[0]+c1[0]+c2[0];
            Fb[i*6+1] = Iat[1]+c1[1]+c2[1];
            Fb[i*6+2] = Iat[2]+c1[2]+c2[2];
            Fb[i*6+3] = Iab[0]+c3[0];
            Fb[i*6+4] = Iab[1]+c3[1];
            Fb[i*6+5] = Iab[2]+c3[2];
#pragma unroll
            for (int k = 0; k < 3; k++){ w[k]=nw[k]; vl[k]=nvl[k]; aw[k]=naw[k]; av[k]=nav[k]; }
        }
        // backward fold (rolled; E recomputed)
#pragma unroll 1
        for (int i = NJ-1; i >= 0; --i){
            float a[3] = { g_ax[3*i], g_ax[3*i+1], g_ax[3*i+2] };
            float f0=Fb[i*6+0], f1=Fb[i*6+1], f2=Fb[i*6+2];
            s_p0[lane*P0S+21+i] -= a[0]*f0 + a[1]*f1 + a[2]*f2;
            if (i > 0){
                float p[3] = { g_pt[3*i], g_pt[3*i+1], g_pt[3*i+2] };
                float snv = s_p0[lane*P0S+i], csv = s_p0[lane*P0S+7+i];
                float E[9]; makeE(a, g_Rt + 9*i, snv, csv, E);
                float ftop[3] = {f0, f1, f2};
                float fbot[3] = {Fb[i*6+3], Fb[i*6+4], Fb[i*6+5]};
                float tm[3], tf[3], cp[3];
                mtv3(E, ftop, tm); mtv3(E, fbot, tf);
                cross3(p, tf, cp);
                Fb[(i-1)*6+0] += tm[0]+cp[0];
                Fb[(i-1)*6+1] += tm[1]+cp[1];
                Fb[(i-1)*6+2] += tm[2]+cp[2];
                Fb[(i-1)*6+3] += tf[0];
                Fb[(i-1)*6+4] += tf[1];
                Fb[(i-1)*6+5] += tf[2];
            }
        }
    }

    __syncthreads();   // the ONLY barrier: publishes s_M (wave1 -> wave0)

    if (act && role == 0){
        // ======== ridge + Cholesky + triangular solves + integrate + store ========
        float Mx[28];
#pragma unroll
        for (int j = 0; j < 28; j++) Mx[j] = s_M[lane*MPAD + j];
#pragma unroll
        for (int i = 0; i < NJ; i++) Mx[MIX(i,i)] += 1e-8f;
#pragma unroll
        for (int k = 0; k < NJ; k++){
            float d = Mx[MIX(k,k)];
#pragma unroll
            for (int j = 0; j < NJ; j++) if (j < k) d -= Mx[MIX(k,j)]*Mx[MIX(k,j)];
            float linv = __builtin_amdgcn_rsqf(d);
            Mx[MIX(k,k)] = linv;
#pragma unroll
            for (int i2 = k+1; i2 < NJ; i2++){
                float s2 = Mx[MIX(i2,k)];
#pragma unroll
                for (int j = 0; j < NJ; j++) if (j < k) s2 -= Mx[MIX(i2,j)]*Mx[MIX(k,j)];
                Mx[MIX(i2,k)] = s2 * linv;
            }
        }
        float rhs[NJ];
#pragma unroll
        for (int i = 0; i < NJ; i++) rhs[i] = s_p0[lane*P0S + 21 + i];
        float y[NJ];
#pragma unroll
        for (int i = 0; i < NJ; i++){
            float s2 = rhs[i];
#pragma unroll
            for (int j = 0; j < NJ; j++) if (j < i) s2 -= Mx[MIX(i,j)]*y[j];
            y[i] = s2 * Mx[MIX(i,i)];
        }
        float z[NJ];
#pragma unroll
        for (int i = NJ-1; i >= 0; i--){
            float s2 = y[i];
#pragma unroll
            for (int j = NJ-1; j >= 0; j--) if (j > i) s2 -= Mx[MIX(j,i)]*z[j];
            z[i] = s2 * Mx[MIX(i,i)];
        }
        float o14[14];
#pragma unroll
        for (int i = 0; i < NJ; i++){
            float qdn = qd[i] + DTF*z[i];
            o14[i]      = q[i] + DTF*qdn;
            o14[NJ + i] = qdn;
        }
        float2* o2 = (float2*)(out + e*14);
#pragma unroll
        for (int i = 0; i < 7; i++){ float2 v; v.x = o14[2*i]; v.y = o14[2*i+1]; o2[i] = v; }
    }
}

extern "C" void kernel_launch(void* const* d_in, const int* in_sizes, int n_in,
                              void* d_out, int out_size, void* d_ws, size_t ws_size,
                              hipStream_t stream) {
    const float* x   = (const float*)d_in[0];
    const float* u   = (const float*)d_in[1];
    const float* ax  = (const float*)d_in[2];
    const float* Rt  = (const float*)d_in[3];
    const float* pt  = (const float*)d_in[4];
    const float* Isp = (const float*)d_in[5];
    float* out = (float*)d_out;
    int B = in_sizes[0] / 14;
    int grid = (B + 63) / 64;
    hipLaunchKernelGGL(panda_step, dim3(grid), dim3(128), 0, stream,
                       x, u, ax, Rt, pt, Isp, out, B);
}